// Round 1
// baseline (350.498 us; speedup 1.0000x reference)
//
#include <hip/hip_runtime.h>
#include <hip/hip_bf16.h>

#define BB 4
#define TT 2048
#define CC 1024
#define HH 16
#define DD 64
#define MM (BB*TT)   // 8192 rows

typedef unsigned short u16;
typedef __bf16 bf16x8 __attribute__((ext_vector_type(8)));
typedef __bf16 bf16x4v __attribute__((ext_vector_type(4)));
typedef u16 u16x8 __attribute__((ext_vector_type(8)));
typedef u16 u16x4 __attribute__((ext_vector_type(4)));
typedef float f32x4 __attribute__((ext_vector_type(4)));

__device__ __forceinline__ u16 f2bf(float f) {
  union { float f; unsigned u; } v; v.f = f;
  unsigned u = v.u;
  return (u16)((u + 0x7fffu + ((u >> 16) & 1u)) >> 16);  // RNE
}
__device__ __forceinline__ float bf2f(u16 s) {
  union { unsigned u; float f; } v; v.u = ((unsigned)s) << 16; return v.f;
}
__device__ __forceinline__ bf16x8 ld_bf16x8(const u16* p) {
  return *reinterpret_cast<const bf16x8*>(p);
}
__device__ __forceinline__ f32x4 zero4() {
  f32x4 z; z[0] = 0.f; z[1] = 0.f; z[2] = 0.f; z[3] = 0.f; return z;
}

// async global->LDS DMA, 16 B/lane. LDS dest = wave-uniform base + lane*16.
__device__ __forceinline__ void gld_lds16(const u16* g, u16* l) {
  __builtin_amdgcn_global_load_lds(
      (const __attribute__((address_space(1))) void*)g,
      (__attribute__((address_space(3))) void*)l, 16, 0, 0);
}
// explicit drain of LDS-DMA: s_waitcnt vmcnt(0)
__device__ __forceinline__ void wait_vm0() { __builtin_amdgcn_s_waitcnt(0x0F70); }

// pull value from lane `srclane` (0..63) of the wave
__device__ __forceinline__ float lane_pull(float x, int srclane) {
  int r = __builtin_amdgcn_ds_bpermute(srclane << 2, __builtin_bit_cast(int, x));
  return __builtin_bit_cast(float, r);
}

// ---------------- merged prep: cast x + transpose-cast both weights ----------------
// blocks [0, NC4B)                : cast x fp32 -> bf16 (float4/lane)
// blocks [NC4B, NC4B+3072)        : W_attn [1024,3072] -> Wt [3072,1024] bf16
// blocks [NC4B+3072, NC4B+4096)   : W_proj [1024,1024] -> Wt [1024,1024] bf16
#define NC4B ((MM * CC / 4) / 256)
__global__ void k_prep(const float* __restrict__ x, u16* __restrict__ xb,
                       const float* __restrict__ Wa, u16* __restrict__ Wab,
                       const float* __restrict__ Wp, u16* __restrict__ Wpb) {
  __shared__ float tile[32][33];
  const int bx = blockIdx.x;
  if (bx < NC4B) {
    int i = bx * 256 + threadIdx.x;
    const float4 v = reinterpret_cast<const float4*>(x)[i];
    u16x4 r; r.x = f2bf(v.x); r.y = f2bf(v.y); r.z = f2bf(v.z); r.w = f2bf(v.w);
    reinterpret_cast<u16x4*>(xb)[i] = r;
    return;
  }
  const float* W; u16* Wt; int K, N, b2;
  if (bx < NC4B + 3072) { W = Wa; Wt = Wab; K = CC; N = 3 * CC; b2 = bx - NC4B; }
  else                  { W = Wp; Wt = Wpb; K = CC; N = CC;     b2 = bx - NC4B - 3072; }
  const int nblk = N / 32;
  const int nb = (b2 % nblk) * 32, kb = (b2 / nblk) * 32;
  const int tx = threadIdx.x & 31, ty = threadIdx.x >> 5;
  #pragma unroll
  for (int i = ty; i < 32; i += 8)
    tile[i][tx] = W[(size_t)(kb + i) * N + nb + tx];
  __syncthreads();
  #pragma unroll
  for (int i = ty; i < 32; i += 8)
    Wt[(size_t)(nb + i) * K + kb + tx] = f2bf(tile[tx][i]);
}

// ---------------- GEMM  C[M,N] = A[M,K](bf16) * Bt[N,K](bf16)^T ----------------
// m97-proven shape: stage(DMA) -> drain -> barrier -> compute -> barrier.
template<int EPI>
__global__ __launch_bounds__(256, 3)
void k_gemm_bt(const u16* __restrict__ A, const u16* __restrict__ Bt,
               float* __restrict__ outF, u16* __restrict__ qb, u16* __restrict__ kb,
               u16* __restrict__ vt, int N, int K)
{
  __shared__ u16 As[128 * 64];
  __shared__ u16 Bs[128 * 64];
  const int tid  = threadIdx.x;
  const int lane = tid & 63, w = tid >> 6;
  const int l16  = lane & 15, quad = lane >> 4;
  const int wr = w >> 1, wc = w & 1;
  const int m0 = blockIdx.y * 128, n0 = blockIdx.x * 128;
  const int lr8 = lane >> 3, lc8 = lane & 7;

  f32x4 acc[4][4];
  #pragma unroll
  for (int i = 0; i < 4; ++i)
    #pragma unroll
    for (int j = 0; j < 4; ++j) acc[i][j] = zero4();

  for (int k0 = 0; k0 < K; k0 += 64) {
    __syncthreads();
    #pragma unroll
    for (int p = 0; p < 4; ++p) {
      const int row = w * 32 + p * 8 + lr8;
      const int cs  = lc8 ^ (row & 7);
      gld_lds16(A  + (size_t)(m0 + row) * K + k0 + cs * 8, &As[(w * 32 + p * 8) * 64]);
      gld_lds16(Bt + (size_t)(n0 + row) * K + k0 + cs * 8, &Bs[(w * 32 + p * 8) * 64]);
    }
    wait_vm0();
    __syncthreads();
    #pragma unroll
    for (int s = 0; s < 2; ++s) {
      bf16x8 af[4], bfr[4];
      #pragma unroll
      for (int i = 0; i < 4; ++i) {
        int mrow = wr * 64 + i * 16 + l16;
        af[i]  = ld_bf16x8(&As[mrow * 64 + ((s * 4 + quad) ^ (l16 & 7)) * 8]);
        int nrow = wc * 64 + i * 16 + l16;
        bfr[i] = ld_bf16x8(&Bs[nrow * 64 + ((s * 4 + quad) ^ (l16 & 7)) * 8]);
      }
      #pragma unroll
      for (int i = 0; i < 4; ++i)
        #pragma unroll
        for (int j = 0; j < 4; ++j)
          acc[i][j] = __builtin_amdgcn_mfma_f32_16x16x32_bf16(af[i], bfr[j], acc[i][j], 0, 0, 0);
    }
  }

  // epilogue: C/D layout col = lane&15, row = quad*4 + reg (m89-verified)
  #pragma unroll
  for (int i = 0; i < 4; ++i) {
    #pragma unroll
    for (int j = 0; j < 4; ++j) {
      const int n = n0 + wc * 64 + j * 16 + l16;
      const int mb = m0 + wr * 64 + i * 16 + quad * 4;   // 4 consecutive m
      if (EPI == 0) {
        #pragma unroll
        for (int r = 0; r < 4; ++r)
          outF[(size_t)(mb + r) * N + n] = acc[i][j][r];
      } else {
        const int b = mb >> 11, tb = mb & 2047;  // t aligned 4, no b-crossing
        if (n < CC) {
          const int h = n >> 6, d = n & 63;
          #pragma unroll
          for (int r = 0; r < 4; ++r)
            qb[(((size_t)(b * HH + h) * TT + tb + r) << 6) + d] = f2bf(acc[i][j][r]);
        } else if (n < 2 * CC) {
          const int n2 = n - CC; const int h = n2 >> 6, d = n2 & 63;
          #pragma unroll
          for (int r = 0; r < 4; ++r)
            kb[(((size_t)(b * HH + h) * TT + tb + r) << 6) + d] = f2bf(acc[i][j][r]);
        } else {
          // v -> [B,H,D,T]: 4 consecutive t at fixed d -> one 8B packed store
          const int n2 = n - 2 * CC; const int h = n2 >> 6, d = n2 & 63;
          u16x4 cv;
          #pragma unroll
          for (int r = 0; r < 4; ++r) cv[r] = f2bf(acc[i][j][r]);
          *reinterpret_cast<u16x4*>(
              vt + ((size_t)(b * HH + h) * DD + d) * TT + tb) = cv;
        }
      }
    }
  }
}

// ---------------- flash attention v9: T14 async reg-staged K/V ----------------
// v8 structure (k-tile 128, S^T layout, direct exp2, deferred l-reduction) with
// the staging converted from global_load_lds + vmcnt(0)-drain to register
// ping-pong: tile t+1's 8 global_load_dwordx4 are issued right after tile t's
// registers are written to LDS, so their HBM/L3 latency hides under tile t's
// entire compute phase. Raw s_barrier + explicit lgkmcnt(0) (NOT __syncthreads,
// which would emit vmcnt(0) and drain the in-flight prefetch). LDS layout and
// swizzles identical to v8 (swizzle moved from global-source to ds_write addr,
// same involution). LDS 40 KB -> 4 blocks/CU unchanged.
__global__ __launch_bounds__(256, 4)
void k_attn(const u16* __restrict__ qb, const u16* __restrict__ kb,
            const u16* __restrict__ vt, u16* __restrict__ y)
{
  __shared__ u16 Ks[128 * 64];
  __shared__ u16 Vs[64 * 128];
  __shared__ u16 QP[64 * 64];   // Q staging (prologue) then P transform (loop)
  const int tid  = threadIdx.x;
  const int lane = tid & 63, w = tid >> 6;
  const int l16  = lane & 15, quad = lane >> 4;
  const int lr8 = lane >> 3, lc8 = lane & 7;

  const int bx = blockIdx.x;
  const int qt = 31 - (bx >> 6);       // heavy q-tiles first
  const int bh = bx & 63;
  const int h  = bh & 15, b = bh >> 4;

  const u16* qptr = qb + ((size_t)bh * TT + qt * 64) * DD;
  const u16* kptr = kb + (size_t)bh * TT * DD;
  const u16* vptr = vt + (size_t)bh * DD * TT;   // [D][T]

  // --- per-lane staging geometry ---
  // K: inst p loads row krow+p*8, 16B chunk lc8 (plain coalesced);
  //    ds_write lands at chunk lc8^(row&7)  => Ks[r][c] = Kglob[r][c^(r&7)]
  const int krow = w * 32 + lr8;
  const u16* kgp = kptr + (size_t)krow * DD + lc8 * 8;
  // V: inst p loads d-row vd+p*4, 16B chunk lane&15;
  //    ds_write at chunk (lane&15)^(d&7)    => Vs[d][c] = Vglob[d][c^(d&7)]
  const int vd = w * 16 + (lane >> 4);
  const u16* vgp = vptr + (size_t)vd * TT + (lane & 15) * 8;

  const int qend = qt * 64;            // diagonal k0
  const int nkt  = (qt >> 1) + 1;      // 128-k tiles

  // prologue: issue tile-0 prefetch FIRST (latency hides under Q staging)
  int4 kr[4], vr[4];
  #pragma unroll
  for (int p = 0; p < 4; ++p)
    kr[p] = *reinterpret_cast<const int4*>(kgp + (size_t)(p * 8) * DD);
  #pragma unroll
  for (int p = 0; p < 4; ++p)
    vr[p] = *reinterpret_cast<const int4*>(vgp + (size_t)(p * 4) * TT);

  // Q: wave-private staging (rows w*16..+16) + frag read; prescale by
  // 1/sqrt(D)*log2(e) -> scores in log2 domain.
  const float qscale = 0.125f * 1.44269504088896340736f;
  #pragma unroll
  for (int p = 0; p < 2; ++p) {
    const int r = w * 16 + p * 8 + lr8;
    u16x8 v = *reinterpret_cast<const u16x8*>(qptr + (size_t)r * DD + lc8 * 8);
    u16x8 o;
    #pragma unroll
    for (int e = 0; e < 8; ++e) o[e] = f2bf(bf2f(v[e]) * qscale);
    *reinterpret_cast<u16x8*>(&QP[r * 64 + (lc8 ^ lr8) * 8]) = o;
  }
  bf16x8 qf[2];
  #pragma unroll
  for (int s = 0; s < 2; ++s)
    qf[s] = ld_bf16x8(&QP[(w * 16 + l16) * 64 + ((s * 4 + quad) ^ (l16 & 7)) * 8]);

  float rsum = 0.f;   // per-lane partial of l for q-row w*16+l16
  f32x4 O[4];
  #pragma unroll
  for (int j = 0; j < 4; ++j) O[j] = zero4();

  for (int kt = 0; kt < nkt; ++kt) {
    // (A) all waves done reading the previous tile from LDS. Raw barrier:
    // no implicit vmcnt drain, so any in-flight prefetch survives it.
    __builtin_amdgcn_s_barrier();
    // write tile kt's registers to LDS (compiler inserts the exact vmcnt
    // wait for kr/vr here -- one full compute phase after they were issued)
    #pragma unroll
    for (int p = 0; p < 4; ++p) {
      const int row = w * 32 + p * 8 + lr8;
      *reinterpret_cast<int4*>(&Ks[row * 64 + ((lc8 ^ (row & 7)) << 3)]) = kr[p];
    }
    #pragma unroll
    for (int p = 0; p < 4; ++p) {
      const int d = vd + p * 4;
      *reinterpret_cast<int4*>(&Vs[d * 128 + (((lane & 15) ^ (d & 7)) << 3)]) = vr[p];
    }
    // issue tile kt+1's prefetch (stays in flight across both barriers)
    if (kt + 1 < nkt) {
      const size_t ko = (size_t)(kt + 1) * 128;
      #pragma unroll
      for (int p = 0; p < 4; ++p)
        kr[p] = *reinterpret_cast<const int4*>(kgp + (ko + (size_t)(p * 8)) * DD);
      #pragma unroll
      for (int p = 0; p < 4; ++p)
        vr[p] = *reinterpret_cast<const int4*>(vgp + ko + (size_t)(p * 4) * TT);
    }
    // own ds_writes drained; "memory" clobber also pins the loads above this
    // point and blocks LDS-read CSE across iterations.
    asm volatile("s_waitcnt lgkmcnt(0)" ::: "memory");
    __builtin_amdgcn_s_barrier();   // (B) everyone's ds_writes visible

    #pragma unroll
    for (int h2 = 0; h2 < 2; ++h2) {
      const int k0 = kt * 128 + h2 * 64;
      if (k0 <= qend) {      // wave-uniform: sub-round at/below diagonal
        // S^T[k][q=l16] : A = K-frag, B = Q-frag (identical operand layouts)
        f32x4 St[4];
        #pragma unroll
        for (int j = 0; j < 4; ++j) St[j] = zero4();
        #pragma unroll
        for (int s = 0; s < 2; ++s) {
          #pragma unroll
          for (int j = 0; j < 4; ++j) {
            bf16x8 kfr = ld_bf16x8(&Ks[(h2 * 64 + j * 16 + l16) * 64 +
                                       ((s * 4 + quad) ^ (l16 & 7)) * 8]);
            St[j] = __builtin_amdgcn_mfma_f32_16x16x32_bf16(kfr, qf[s], St[j], 0, 0, 0);
          }
        }
        if (k0 == qend) {  // diagonal: causal mask (local: k > q -> -inf)
          const int qg = w * 16 + l16;
          #pragma unroll
          for (int j = 0; j < 4; ++j)
            #pragma unroll
            for (int r = 0; r < 4; ++r)
              if (j * 16 + quad * 4 + r > qg) St[j][r] = -__builtin_inff();
        }

        // p = 2^S directly (|S| << 120; masked -inf -> 0). l per-lane.
        #pragma unroll
        for (int j = 0; j < 4; ++j)
          #pragma unroll
          for (int r = 0; r < 4; ++r) {
            float p = __builtin_amdgcn_exp2f(St[j][r]);
            St[j][r] = p;
            rsum += p;
          }

        // P repack: lane holds k-contiguous quads of q-row l16 -> b64 writes
        #pragma unroll
        for (int j = 0; j < 4; ++j) {
          union { bf16x4v bv; u16x4 u; } cv;
          cv.bv[0] = (__bf16)St[j][0]; cv.bv[1] = (__bf16)St[j][1];
          cv.bv[2] = (__bf16)St[j][2]; cv.bv[3] = (__bf16)St[j][3];
          const int c = j * 2 + (quad >> 1);
          const int off = w * 1024 + l16 * 64 + ((c ^ (l16 & 7)) << 3) + ((quad & 1) << 2);
          *reinterpret_cast<u16x4*>(&QP[off]) = cv.u;
        }
        #pragma unroll
        for (int s = 0; s < 2; ++s) {
          bf16x8 pf = ld_bf16x8(&QP[w * 1024 + l16 * 64 +
                                    ((s * 4 + quad) ^ (l16 & 7)) * 8]);
          #pragma unroll
          for (int j = 0; j < 4; ++j) {
            bf16x8 vf = ld_bf16x8(&Vs[(j * 16 + l16) * 128 +
                                      ((h2 * 8 + s * 4 + quad) ^ (l16 & 7)) * 8]);
            O[j] = __builtin_amdgcn_mfma_f32_16x16x32_bf16(pf, vf, O[j], 0, 0, 0);
          }
        }
      }
    }
  }

  // epilogue: reduce l across the 4 quads holding this q-row, O /= l, write y
  rsum += __shfl_xor(rsum, 16);
  rsum += __shfl_xor(rsum, 32);
  const float linv = 1.0f / rsum;
  f32x4 lv;
  #pragma unroll
  for (int r = 0; r < 4; ++r) lv[r] = lane_pull(linv, quad * 4 + r);
  #pragma unroll
  for (int j = 0; j < 4; ++j) {
    O[j] *= lv;
    #pragma unroll
    for (int r = 0; r < 4; ++r) {
      int t  = qt * 64 + w * 16 + quad * 4 + r;
      int ch = h * 64 + j * 16 + l16;
      y[(size_t)(b * TT + t) * CC + ch] = f2bf(O[j][r]);
    }
  }
}

extern "C" void kernel_launch(void* const* d_in, const int* in_sizes, int n_in,
                              void* d_out, int out_size, void* d_ws, size_t ws_size,
                              hipStream_t stream) {
  const float* x  = (const float*)d_in[0];   // [B,T,C]
  const float* Wa = (const float*)d_in[1];   // [C,3C]
  const float* Wp = (const float*)d_in[2];   // [C,C]
  float* out = (float*)d_out;                // [B,T,C] fp32

  u16* ws   = (u16*)d_ws;
  u16* xb   = ws;                             // M*C
  u16* Wab  = xb   + (size_t)MM * CC;         // 3C*C (W_attn^T)
  u16* Wpb  = Wab  + (size_t)3 * CC * CC;     // C*C  (W_proj^T)
  u16* qbuf = Wpb  + (size_t)CC * CC;         // [B,H,T,D]
  u16* kbuf = qbuf + (size_t)MM * CC;         // [B,H,T,D]
  u16* vtb  = kbuf + (size_t)MM * CC;         // [B,H,D,T]
  u16* yb   = vtb  + (size_t)MM * CC;         // [B,T,C]

  k_prep<<<NC4B + 3072 + 1024, 256, 0, stream>>>(x, xb, Wa, Wab, Wp, Wpb);
  k_gemm_bt<1><<<dim3(3 * CC / 128, MM / 128), 256, 0, stream>>>(
      xb, Wab, nullptr, qbuf, kbuf, vtb, 3 * CC, CC);
  k_attn<<<64 * 32, 256, 0, stream>>>(qbuf, kbuf, vtb, yb);
  k_gemm_bt<0><<<dim3(CC / 128, MM / 128), 256, 0, stream>>>(
      yb, Wpb, out, nullptr, nullptr, nullptr, CC, CC);
}

// Round 2
// 224.922 us; speedup vs baseline: 1.5583x; 1.5583x over previous
//
#include <hip/hip_runtime.h>
#include <hip/hip_bf16.h>

#define BB 4
#define TT 2048
#define CC 1024
#define HH 16
#define DD 64
#define MM (BB*TT)   // 8192 rows

typedef unsigned short u16;
typedef __bf16 bf16x8 __attribute__((ext_vector_type(8)));
typedef __bf16 bf16x4v __attribute__((ext_vector_type(4)));
typedef u16 u16x8 __attribute__((ext_vector_type(8)));
typedef u16 u16x4 __attribute__((ext_vector_type(4)));
typedef float f32x4 __attribute__((ext_vector_type(4)));

__device__ __forceinline__ u16 f2bf(float f) {
  union { float f; unsigned u; } v; v.f = f;
  unsigned u = v.u;
  return (u16)((u + 0x7fffu + ((u >> 16) & 1u)) >> 16);  // RNE
}
__device__ __forceinline__ float bf2f(u16 s) {
  union { unsigned u; float f; } v; v.u = ((unsigned)s) << 16; return v.f;
}
__device__ __forceinline__ bf16x8 ld_bf16x8(const u16* p) {
  return *reinterpret_cast<const bf16x8*>(p);
}
__device__ __forceinline__ f32x4 zero4() {
  f32x4 z; z[0] = 0.f; z[1] = 0.f; z[2] = 0.f; z[3] = 0.f; return z;
}

// async global->LDS DMA, 16 B/lane. LDS dest = wave-uniform base + lane*16.
__device__ __forceinline__ void gld_lds16(const u16* g, u16* l) {
  __builtin_amdgcn_global_load_lds(
      (const __attribute__((address_space(1))) void*)g,
      (__attribute__((address_space(3))) void*)l, 16, 0, 0);
}
// explicit drain of LDS-DMA: s_waitcnt vmcnt(0)
__device__ __forceinline__ void wait_vm0() { __builtin_amdgcn_s_waitcnt(0x0F70); }

// pull value from lane `srclane` (0..63) of the wave
__device__ __forceinline__ float lane_pull(float x, int srclane) {
  int r = __builtin_amdgcn_ds_bpermute(srclane << 2, __builtin_bit_cast(int, x));
  return __builtin_bit_cast(float, r);
}

// ---------------- merged prep: cast x + transpose-cast both weights ----------------
// blocks [0, NC4B)                : cast x fp32 -> bf16 (float4/lane)
// blocks [NC4B, NC4B+3072)        : W_attn [1024,3072] -> Wt [3072,1024] bf16
// blocks [NC4B+3072, NC4B+4096)   : W_proj [1024,1024] -> Wt [1024,1024] bf16
#define NC4B ((MM * CC / 4) / 256)
__global__ void k_prep(const float* __restrict__ x, u16* __restrict__ xb,
                       const float* __restrict__ Wa, u16* __restrict__ Wab,
                       const float* __restrict__ Wp, u16* __restrict__ Wpb) {
  __shared__ float tile[32][33];
  const int bx = blockIdx.x;
  if (bx < NC4B) {
    int i = bx * 256 + threadIdx.x;
    const float4 v = reinterpret_cast<const float4*>(x)[i];
    u16x4 r; r.x = f2bf(v.x); r.y = f2bf(v.y); r.z = f2bf(v.z); r.w = f2bf(v.w);
    reinterpret_cast<u16x4*>(xb)[i] = r;
    return;
  }
  const float* W; u16* Wt; int K, N, b2;
  if (bx < NC4B + 3072) { W = Wa; Wt = Wab; K = CC; N = 3 * CC; b2 = bx - NC4B; }
  else                  { W = Wp; Wt = Wpb; K = CC; N = CC;     b2 = bx - NC4B - 3072; }
  const int nblk = N / 32;
  const int nb = (b2 % nblk) * 32, kb = (b2 / nblk) * 32;
  const int tx = threadIdx.x & 31, ty = threadIdx.x >> 5;
  #pragma unroll
  for (int i = ty; i < 32; i += 8)
    tile[i][tx] = W[(size_t)(kb + i) * N + nb + tx];
  __syncthreads();
  #pragma unroll
  for (int i = ty; i < 32; i += 8)
    Wt[(size_t)(nb + i) * K + kb + tx] = f2bf(tile[tx][i]);
}

// ---------------- GEMM  C[M,N] = A[M,K](bf16) * Bt[N,K](bf16)^T ----------------
// m97-proven shape: stage(DMA) -> drain -> barrier -> compute -> barrier.
template<int EPI>
__global__ __launch_bounds__(256, 3)
void k_gemm_bt(const u16* __restrict__ A, const u16* __restrict__ Bt,
               float* __restrict__ outF, u16* __restrict__ qb, u16* __restrict__ kb,
               u16* __restrict__ vt, int N, int K)
{
  __shared__ u16 As[128 * 64];
  __shared__ u16 Bs[128 * 64];
  const int tid  = threadIdx.x;
  const int lane = tid & 63, w = tid >> 6;
  const int l16  = lane & 15, quad = lane >> 4;
  const int wr = w >> 1, wc = w & 1;
  const int m0 = blockIdx.y * 128, n0 = blockIdx.x * 128;
  const int lr8 = lane >> 3, lc8 = lane & 7;

  f32x4 acc[4][4];
  #pragma unroll
  for (int i = 0; i < 4; ++i)
    #pragma unroll
    for (int j = 0; j < 4; ++j) acc[i][j] = zero4();

  for (int k0 = 0; k0 < K; k0 += 64) {
    __syncthreads();
    #pragma unroll
    for (int p = 0; p < 4; ++p) {
      const int row = w * 32 + p * 8 + lr8;
      const int cs  = lc8 ^ (row & 7);
      gld_lds16(A  + (size_t)(m0 + row) * K + k0 + cs * 8, &As[(w * 32 + p * 8) * 64]);
      gld_lds16(Bt + (size_t)(n0 + row) * K + k0 + cs * 8, &Bs[(w * 32 + p * 8) * 64]);
    }
    wait_vm0();
    __syncthreads();
    #pragma unroll
    for (int s = 0; s < 2; ++s) {
      bf16x8 af[4], bfr[4];
      #pragma unroll
      for (int i = 0; i < 4; ++i) {
        int mrow = wr * 64 + i * 16 + l16;
        af[i]  = ld_bf16x8(&As[mrow * 64 + ((s * 4 + quad) ^ (l16 & 7)) * 8]);
        int nrow = wc * 64 + i * 16 + l16;
        bfr[i] = ld_bf16x8(&Bs[nrow * 64 + ((s * 4 + quad) ^ (l16 & 7)) * 8]);
      }
      #pragma unroll
      for (int i = 0; i < 4; ++i)
        #pragma unroll
        for (int j = 0; j < 4; ++j)
          acc[i][j] = __builtin_amdgcn_mfma_f32_16x16x32_bf16(af[i], bfr[j], acc[i][j], 0, 0, 0);
    }
  }

  // epilogue: C/D layout col = lane&15, row = quad*4 + reg (m89-verified)
  #pragma unroll
  for (int i = 0; i < 4; ++i) {
    #pragma unroll
    for (int j = 0; j < 4; ++j) {
      const int n = n0 + wc * 64 + j * 16 + l16;
      const int mb = m0 + wr * 64 + i * 16 + quad * 4;   // 4 consecutive m
      if (EPI == 0) {
        #pragma unroll
        for (int r = 0; r < 4; ++r)
          outF[(size_t)(mb + r) * N + n] = acc[i][j][r];
      } else {
        const int b = mb >> 11, tb = mb & 2047;  // t aligned 4, no b-crossing
        if (n < CC) {
          const int h = n >> 6, d = n & 63;
          #pragma unroll
          for (int r = 0; r < 4; ++r)
            qb[(((size_t)(b * HH + h) * TT + tb + r) << 6) + d] = f2bf(acc[i][j][r]);
        } else if (n < 2 * CC) {
          const int n2 = n - CC; const int h = n2 >> 6, d = n2 & 63;
          #pragma unroll
          for (int r = 0; r < 4; ++r)
            kb[(((size_t)(b * HH + h) * TT + tb + r) << 6) + d] = f2bf(acc[i][j][r]);
        } else {
          // v -> [B,H,D,T]: 4 consecutive t at fixed d -> one 8B packed store
          const int n2 = n - 2 * CC; const int h = n2 >> 6, d = n2 & 63;
          u16x4 cv;
          #pragma unroll
          for (int r = 0; r < 4; ++r) cv[r] = f2bf(acc[i][j][r]);
          *reinterpret_cast<u16x4*>(
              vt + ((size_t)(b * HH + h) * DD + d) * TT + tb) = cv;
        }
      }
    }
  }
}

// ---------------- flash attention v10: T14 async reg-staged K/V, spill-fixed ----
// v9's int4 kr[4]/vr[4] ARRAYS were demoted to scratch (VGPR_Count stayed 52,
// WRITE_SIZE 16->542 MB = 32 KB/block/iter spill store+reload). v10 replaces
// them with NAMED SCALARS (kr0..kr3, vr0..vr3) and hand-unrolls every access,
// so there is no alloca to mis-promote. Structure otherwise identical to v9:
// issue tile t+1's 8 global_load_dwordx4 right after tile t's ds_writes; raw
// s_barrier (no vmcnt drain) keeps them in flight across the whole compute
// phase; the compiler's own vmcnt wait for the staging regs lands at the next
// iteration's ds_write. LDS 40 KB -> 4 blocks/CU unchanged.
__global__ __launch_bounds__(256, 4)
void k_attn(const u16* __restrict__ qb, const u16* __restrict__ kb,
            const u16* __restrict__ vt, u16* __restrict__ y)
{
  __shared__ u16 Ks[128 * 64];
  __shared__ u16 Vs[64 * 128];
  __shared__ u16 QP[64 * 64];   // Q staging (prologue) then P transform (loop)
  const int tid  = threadIdx.x;
  const int lane = tid & 63, w = tid >> 6;
  const int l16  = lane & 15, quad = lane >> 4;
  const int lr8 = lane >> 3, lc8 = lane & 7;

  const int bx = blockIdx.x;
  const int qt = 31 - (bx >> 6);       // heavy q-tiles first
  const int bh = bx & 63;
  const int h  = bh & 15, b = bh >> 4;

  const u16* qptr = qb + ((size_t)bh * TT + qt * 64) * DD;
  const u16* kptr = kb + (size_t)bh * TT * DD;
  const u16* vptr = vt + (size_t)bh * DD * TT;   // [D][T]

  // --- per-lane staging geometry ---
  // K: chunk lc8 of row krow+p*8 (global, plain coalesced); ds_write lands at
  //    chunk lc8^lr8 (row&7 == lr8)  => Ks[r][c] = Kglob[r][c^(r&7)]
  const int krow = w * 32 + lr8;
  const u16* kgp = kptr + (size_t)krow * DD + lc8 * 8;
  // V: chunk lane&15 of d-row vd+p*4; ds_write at chunk (lane&15)^(d&7)
  //    => Vs[d][c] = Vglob[d][c^(d&7)].  d&7 = quad + (p&1)*4.
  const int vd = w * 16 + quad;
  const u16* vgp = vptr + (size_t)vd * TT + (lane & 15) * 8;

  const int qend = qt * 64;            // diagonal k0
  const int nkt  = (qt >> 1) + 1;      // 128-k tiles

  // staging registers: NAMED SCALARS, never an array (v9 spill fix)
  int4 kr0, kr1, kr2, kr3, vr0, vr1, vr2, vr3;

  // prologue: issue tile-0 prefetch FIRST (latency hides under Q staging)
  kr0 = *reinterpret_cast<const int4*>(kgp + (size_t)( 0) * DD);
  kr1 = *reinterpret_cast<const int4*>(kgp + (size_t)( 8) * DD);
  kr2 = *reinterpret_cast<const int4*>(kgp + (size_t)(16) * DD);
  kr3 = *reinterpret_cast<const int4*>(kgp + (size_t)(24) * DD);
  vr0 = *reinterpret_cast<const int4*>(vgp + (size_t)( 0) * TT);
  vr1 = *reinterpret_cast<const int4*>(vgp + (size_t)( 4) * TT);
  vr2 = *reinterpret_cast<const int4*>(vgp + (size_t)( 8) * TT);
  vr3 = *reinterpret_cast<const int4*>(vgp + (size_t)(12) * TT);

  // Q: wave-private staging (rows w*16..+16) + frag read; prescale by
  // 1/sqrt(D)*log2(e) -> scores in log2 domain.
  const float qscale = 0.125f * 1.44269504088896340736f;
  #pragma unroll
  for (int p = 0; p < 2; ++p) {
    const int r = w * 16 + p * 8 + lr8;
    u16x8 v = *reinterpret_cast<const u16x8*>(qptr + (size_t)r * DD + lc8 * 8);
    u16x8 o;
    #pragma unroll
    for (int e = 0; e < 8; ++e) o[e] = f2bf(bf2f(v[e]) * qscale);
    *reinterpret_cast<u16x8*>(&QP[r * 64 + (lc8 ^ lr8) * 8]) = o;
  }
  bf16x8 qf[2];
  #pragma unroll
  for (int s = 0; s < 2; ++s)
    qf[s] = ld_bf16x8(&QP[(w * 16 + l16) * 64 + ((s * 4 + quad) ^ (l16 & 7)) * 8]);

  float rsum = 0.f;   // per-lane partial of l for q-row w*16+l16
  f32x4 O[4];
  #pragma unroll
  for (int j = 0; j < 4; ++j) O[j] = zero4();

  // LDS write addresses (loop-invariant)
  u16* const ksw = &Ks[(w * 32 + lr8) * 64 + ((lc8 ^ lr8) << 3)];      // +p*512
  const int vc0 = ((lane & 15) ^ quad) << 3;          // p even chunk
  const int vc1 = ((lane & 15) ^ (quad + 4)) << 3;    // p odd chunk
  u16* const vsw = &Vs[vd * 128];                     // +p*512 + vc{0,1}

  for (int kt = 0; kt < nkt; ++kt) {
    // (A) all waves done reading the previous tile from LDS. Raw barrier:
    // no implicit vmcnt drain, so the in-flight prefetch survives it.
    __builtin_amdgcn_s_barrier();
    // write tile kt's registers to LDS (compiler inserts the exact vmcnt
    // wait for kr*/vr* here -- one full compute phase after they were issued)
    *reinterpret_cast<int4*>(ksw + 0 * 512) = kr0;
    *reinterpret_cast<int4*>(ksw + 1 * 512) = kr1;
    *reinterpret_cast<int4*>(ksw + 2 * 512) = kr2;
    *reinterpret_cast<int4*>(ksw + 3 * 512) = kr3;
    *reinterpret_cast<int4*>(vsw + 0 * 512 + vc0) = vr0;
    *reinterpret_cast<int4*>(vsw + 1 * 512 + vc1) = vr1;
    *reinterpret_cast<int4*>(vsw + 2 * 512 + vc0) = vr2;
    *reinterpret_cast<int4*>(vsw + 3 * 512 + vc1) = vr3;
    // issue tile kt+1's prefetch (stays in flight across both barriers)
    if (kt + 1 < nkt) {
      const u16* kg = kgp + (size_t)(kt + 1) * 128 * DD;
      const u16* vg = vgp + (size_t)(kt + 1) * 128;
      kr0 = *reinterpret_cast<const int4*>(kg + (size_t)( 0) * DD);
      kr1 = *reinterpret_cast<const int4*>(kg + (size_t)( 8) * DD);
      kr2 = *reinterpret_cast<const int4*>(kg + (size_t)(16) * DD);
      kr3 = *reinterpret_cast<const int4*>(kg + (size_t)(24) * DD);
      vr0 = *reinterpret_cast<const int4*>(vg + (size_t)( 0) * TT);
      vr1 = *reinterpret_cast<const int4*>(vg + (size_t)( 4) * TT);
      vr2 = *reinterpret_cast<const int4*>(vg + (size_t)( 8) * TT);
      vr3 = *reinterpret_cast<const int4*>(vg + (size_t)(12) * TT);
    }
    // own ds_writes drained; "memory" clobber also pins the loads above this
    // point and blocks LDS-read CSE across iterations.
    asm volatile("s_waitcnt lgkmcnt(0)" ::: "memory");
    __builtin_amdgcn_s_barrier();   // (B) everyone's ds_writes visible

    #pragma unroll
    for (int h2 = 0; h2 < 2; ++h2) {
      const int k0 = kt * 128 + h2 * 64;
      if (k0 <= qend) {      // wave-uniform: sub-round at/below diagonal
        // S^T[k][q=l16] : A = K-frag, B = Q-frag (identical operand layouts)
        f32x4 St[4];
        #pragma unroll
        for (int j = 0; j < 4; ++j) St[j] = zero4();
        #pragma unroll
        for (int s = 0; s < 2; ++s) {
          #pragma unroll
          for (int j = 0; j < 4; ++j) {
            bf16x8 kfr = ld_bf16x8(&Ks[(h2 * 64 + j * 16 + l16) * 64 +
                                       ((s * 4 + quad) ^ (l16 & 7)) * 8]);
            St[j] = __builtin_amdgcn_mfma_f32_16x16x32_bf16(kfr, qf[s], St[j], 0, 0, 0);
          }
        }
        if (k0 == qend) {  // diagonal: causal mask (local: k > q -> -inf)
          const int qg = w * 16 + l16;
          #pragma unroll
          for (int j = 0; j < 4; ++j)
            #pragma unroll
            for (int r = 0; r < 4; ++r)
              if (j * 16 + quad * 4 + r > qg) St[j][r] = -__builtin_inff();
        }

        // p = 2^S directly (|S| << 120; masked -inf -> 0). l per-lane.
        #pragma unroll
        for (int j = 0; j < 4; ++j)
          #pragma unroll
          for (int r = 0; r < 4; ++r) {
            float p = __builtin_amdgcn_exp2f(St[j][r]);
            St[j][r] = p;
            rsum += p;
          }

        // P repack: lane holds k-contiguous quads of q-row l16 -> b64 writes
        #pragma unroll
        for (int j = 0; j < 4; ++j) {
          union { bf16x4v bv; u16x4 u; } cv;
          cv.bv[0] = (__bf16)St[j][0]; cv.bv[1] = (__bf16)St[j][1];
          cv.bv[2] = (__bf16)St[j][2]; cv.bv[3] = (__bf16)St[j][3];
          const int c = j * 2 + (quad >> 1);
          const int off = w * 1024 + l16 * 64 + ((c ^ (l16 & 7)) << 3) + ((quad & 1) << 2);
          *reinterpret_cast<u16x4*>(&QP[off]) = cv.u;
        }
        #pragma unroll
        for (int s = 0; s < 2; ++s) {
          bf16x8 pf = ld_bf16x8(&QP[w * 1024 + l16 * 64 +
                                    ((s * 4 + quad) ^ (l16 & 7)) * 8]);
          #pragma unroll
          for (int j = 0; j < 4; ++j) {
            bf16x8 vf = ld_bf16x8(&Vs[(j * 16 + l16) * 128 +
                                      ((h2 * 8 + s * 4 + quad) ^ (l16 & 7)) * 8]);
            O[j] = __builtin_amdgcn_mfma_f32_16x16x32_bf16(pf, vf, O[j], 0, 0, 0);
          }
        }
      }
    }
  }

  // epilogue: reduce l across the 4 quads holding this q-row, O /= l, write y
  rsum += __shfl_xor(rsum, 16);
  rsum += __shfl_xor(rsum, 32);
  const float linv = 1.0f / rsum;
  f32x4 lv;
  #pragma unroll
  for (int r = 0; r < 4; ++r) lv[r] = lane_pull(linv, quad * 4 + r);
  #pragma unroll
  for (int j = 0; j < 4; ++j) {
    O[j] *= lv;
    #pragma unroll
    for (int r = 0; r < 4; ++r) {
      int t  = qt * 64 + w * 16 + quad * 4 + r;
      int ch = h * 64 + j * 16 + l16;
      y[(size_t)(b * TT + t) * CC + ch] = f2bf(O[j][r]);
    }
  }
}

extern "C" void kernel_launch(void* const* d_in, const int* in_sizes, int n_in,
                              void* d_out, int out_size, void* d_ws, size_t ws_size,
                              hipStream_t stream) {
  const float* x  = (const float*)d_in[0];   // [B,T,C]
  const float* Wa = (const float*)d_in[1];   // [C,3C]
  const float* Wp = (const float*)d_in[2];   // [C,C]
  float* out = (float*)d_out;                // [B,T,C] fp32

  u16* ws   = (u16*)d_ws;
  u16* xb   = ws;                             // M*C
  u16* Wab  = xb   + (size_t)MM * CC;         // 3C*C (W_attn^T)
  u16* Wpb  = Wab  + (size_t)3 * CC * CC;     // C*C  (W_proj^T)
  u16* qbuf = Wpb  + (size_t)CC * CC;         // [B,H,T,D]
  u16* kbuf = qbuf + (size_t)MM * CC;         // [B,H,T,D]
  u16* vtb  = kbuf + (size_t)MM * CC;         // [B,H,D,T]
  u16* yb   = vtb  + (size_t)MM * CC;         // [B,T,C]

  k_prep<<<NC4B + 3072 + 1024, 256, 0, stream>>>(x, xb, Wa, Wab, Wp, Wpb);
  k_gemm_bt<1><<<dim3(3 * CC / 128, MM / 128), 256, 0, stream>>>(
      xb, Wab, nullptr, qbuf, kbuf, vtb, 3 * CC, CC);
  k_attn<<<64 * 32, 256, 0, stream>>>(qbuf, kbuf, vtb, yb);
  k_gemm_bt<0><<<dim3(CC / 128, MM / 128), 256, 0, stream>>>(
      yb, Wpb, out, nullptr, nullptr, nullptr, CC, CC);
}

// Round 3
// 213.952 us; speedup vs baseline: 1.6382x; 1.0513x over previous
//
#include <hip/hip_runtime.h>
#include <hip/hip_bf16.h>

#define BB 4
#define TT 2048
#define CC 1024
#define HH 16
#define DD 64
#define MM (BB*TT)   // 8192 rows

typedef unsigned short u16;
typedef __bf16 bf16x8 __attribute__((ext_vector_type(8)));
typedef __bf16 bf16x4v __attribute__((ext_vector_type(4)));
typedef u16 u16x8 __attribute__((ext_vector_type(8)));
typedef u16 u16x4 __attribute__((ext_vector_type(4)));
typedef float f32x4 __attribute__((ext_vector_type(4)));

__device__ __forceinline__ u16 f2bf(float f) {
  union { float f; unsigned u; } v; v.f = f;
  unsigned u = v.u;
  return (u16)((u + 0x7fffu + ((u >> 16) & 1u)) >> 16);  // RNE
}
__device__ __forceinline__ float bf2f(u16 s) {
  union { unsigned u; float f; } v; v.u = ((unsigned)s) << 16; return v.f;
}
__device__ __forceinline__ bf16x8 ld_bf16x8(const u16* p) {
  return *reinterpret_cast<const bf16x8*>(p);
}
__device__ __forceinline__ f32x4 zero4() {
  f32x4 z; z[0] = 0.f; z[1] = 0.f; z[2] = 0.f; z[3] = 0.f; return z;
}

// async global->LDS DMA, 16 B/lane. LDS dest = wave-uniform base + lane*16.
__device__ __forceinline__ void gld_lds16(const u16* g, u16* l) {
  __builtin_amdgcn_global_load_lds(
      (const __attribute__((address_space(1))) void*)g,
      (__attribute__((address_space(3))) void*)l, 16, 0, 0);
}
// explicit drain of LDS-DMA: s_waitcnt vmcnt(0)
__device__ __forceinline__ void wait_vm0() { __builtin_amdgcn_s_waitcnt(0x0F70); }

// pull value from lane `srclane` (0..63) of the wave
__device__ __forceinline__ float lane_pull(float x, int srclane) {
  int r = __builtin_amdgcn_ds_bpermute(srclane << 2, __builtin_bit_cast(int, x));
  return __builtin_bit_cast(float, r);
}

// ---------------- merged prep: cast x + transpose-cast both weights ----------------
// blocks [0, NC4B)                : cast x fp32 -> bf16 (float4/lane)
// blocks [NC4B, NC4B+3072)        : W_attn [1024,3072] -> Wt [3072,1024] bf16
// blocks [NC4B+3072, NC4B+4096)   : W_proj [1024,1024] -> Wt [1024,1024] bf16
#define NC4B ((MM * CC / 4) / 256)
__global__ void k_prep(const float* __restrict__ x, u16* __restrict__ xb,
                       const float* __restrict__ Wa, u16* __restrict__ Wab,
                       const float* __restrict__ Wp, u16* __restrict__ Wpb) {
  __shared__ float tile[32][33];
  const int bx = blockIdx.x;
  if (bx < NC4B) {
    int i = bx * 256 + threadIdx.x;
    const float4 v = reinterpret_cast<const float4*>(x)[i];
    u16x4 r; r.x = f2bf(v.x); r.y = f2bf(v.y); r.z = f2bf(v.z); r.w = f2bf(v.w);
    reinterpret_cast<u16x4*>(xb)[i] = r;
    return;
  }
  const float* W; u16* Wt; int K, N, b2;
  if (bx < NC4B + 3072) { W = Wa; Wt = Wab; K = CC; N = 3 * CC; b2 = bx - NC4B; }
  else                  { W = Wp; Wt = Wpb; K = CC; N = CC;     b2 = bx - NC4B - 3072; }
  const int nblk = N / 32;
  const int nb = (b2 % nblk) * 32, kb = (b2 / nblk) * 32;
  const int tx = threadIdx.x & 31, ty = threadIdx.x >> 5;
  #pragma unroll
  for (int i = ty; i < 32; i += 8)
    tile[i][tx] = W[(size_t)(kb + i) * N + nb + tx];
  __syncthreads();
  #pragma unroll
  for (int i = ty; i < 32; i += 8)
    Wt[(size_t)(nb + i) * K + kb + tx] = f2bf(tile[tx][i]);
}

// ---------------- GEMM  C[M,N] = A[M,K](bf16) * Bt[N,K](bf16)^T ----------------
// m97-proven shape: stage(DMA) -> drain -> barrier -> compute -> barrier.
template<int EPI>
__global__ __launch_bounds__(256, 3)
void k_gemm_bt(const u16* __restrict__ A, const u16* __restrict__ Bt,
               float* __restrict__ outF, u16* __restrict__ qb, u16* __restrict__ kb,
               u16* __restrict__ vt, int N, int K)
{
  __shared__ u16 As[128 * 64];
  __shared__ u16 Bs[128 * 64];
  const int tid  = threadIdx.x;
  const int lane = tid & 63, w = tid >> 6;
  const int l16  = lane & 15, quad = lane >> 4;
  const int wr = w >> 1, wc = w & 1;
  const int m0 = blockIdx.y * 128, n0 = blockIdx.x * 128;
  const int lr8 = lane >> 3, lc8 = lane & 7;

  f32x4 acc[4][4];
  #pragma unroll
  for (int i = 0; i < 4; ++i)
    #pragma unroll
    for (int j = 0; j < 4; ++j) acc[i][j] = zero4();

  for (int k0 = 0; k0 < K; k0 += 64) {
    __syncthreads();
    #pragma unroll
    for (int p = 0; p < 4; ++p) {
      const int row = w * 32 + p * 8 + lr8;
      const int cs  = lc8 ^ (row & 7);
      gld_lds16(A  + (size_t)(m0 + row) * K + k0 + cs * 8, &As[(w * 32 + p * 8) * 64]);
      gld_lds16(Bt + (size_t)(n0 + row) * K + k0 + cs * 8, &Bs[(w * 32 + p * 8) * 64]);
    }
    wait_vm0();
    __syncthreads();
    #pragma unroll
    for (int s = 0; s < 2; ++s) {
      bf16x8 af[4], bfr[4];
      #pragma unroll
      for (int i = 0; i < 4; ++i) {
        int mrow = wr * 64 + i * 16 + l16;
        af[i]  = ld_bf16x8(&As[mrow * 64 + ((s * 4 + quad) ^ (l16 & 7)) * 8]);
        int nrow = wc * 64 + i * 16 + l16;
        bfr[i] = ld_bf16x8(&Bs[nrow * 64 + ((s * 4 + quad) ^ (l16 & 7)) * 8]);
      }
      #pragma unroll
      for (int i = 0; i < 4; ++i)
        #pragma unroll
        for (int j = 0; j < 4; ++j)
          acc[i][j] = __builtin_amdgcn_mfma_f32_16x16x32_bf16(af[i], bfr[j], acc[i][j], 0, 0, 0);
    }
  }

  // epilogue: C/D layout col = lane&15, row = quad*4 + reg (m89-verified)
  #pragma unroll
  for (int i = 0; i < 4; ++i) {
    #pragma unroll
    for (int j = 0; j < 4; ++j) {
      const int n = n0 + wc * 64 + j * 16 + l16;
      const int mb = m0 + wr * 64 + i * 16 + quad * 4;   // 4 consecutive m
      if (EPI == 0) {
        #pragma unroll
        for (int r = 0; r < 4; ++r)
          outF[(size_t)(mb + r) * N + n] = acc[i][j][r];
      } else {
        const int b = mb >> 11, tb = mb & 2047;  // t aligned 4, no b-crossing
        if (n < CC) {
          const int h = n >> 6, d = n & 63;
          #pragma unroll
          for (int r = 0; r < 4; ++r)
            qb[(((size_t)(b * HH + h) * TT + tb + r) << 6) + d] = f2bf(acc[i][j][r]);
        } else if (n < 2 * CC) {
          const int n2 = n - CC; const int h = n2 >> 6, d = n2 & 63;
          #pragma unroll
          for (int r = 0; r < 4; ++r)
            kb[(((size_t)(b * HH + h) * TT + tb + r) << 6) + d] = f2bf(acc[i][j][r]);
        } else {
          // v -> [B,H,D,T]: 4 consecutive t at fixed d -> one 8B packed store
          const int n2 = n - 2 * CC; const int h = n2 >> 6, d = n2 & 63;
          u16x4 cv;
          #pragma unroll
          for (int r = 0; r < 4; ++r) cv[r] = f2bf(acc[i][j][r]);
          *reinterpret_cast<u16x4*>(
              vt + ((size_t)(b * HH + h) * DD + d) * TT + tb) = cv;
        }
      }
    }
  }
}

// ---------------- flash attention v11: 2 q-groups per wave (LDS-BW fix) ----------
// v8/v10 were LDS-read-BW-bound (~2.5 GB ds_read_b128/dispatch at ~85 B/cyc/CU
// ~= the whole 65 us). v11 doubles q per wave: block q-tile = 128 rows, each
// wave owns TWO 16-row q-groups, so the shared K-frag and V-frag reads are
// loaded ONCE and feed both groups' MFMAs. Per-wave per 64k sub-round:
// 20 b128 for 32 q (vs 36 before) -> 1.8x LDS-read reduction; K/V staging per
// q also halves (one tile serves 128 q). QP holds both groups' P (16 KB) so
// vf reads are shared. LDS 48 KB -> 3 blocks/CU. Staging = proven v8
// global_load_lds path (latency is not the bottleneck; v10 A/B showed null).
__global__ __launch_bounds__(256, 3)
void k_attn(const u16* __restrict__ qb, const u16* __restrict__ kb,
            const u16* __restrict__ vt, u16* __restrict__ y)
{
  __shared__ u16 Ks[128 * 64];   // K tile [128 k][64 d]   (Q staging in prologue)
  __shared__ u16 Vs[64 * 128];   // V tile [64 d][128 t]
  __shared__ u16 QP[8 * 1024];   // P transform: (wave,group) -> 1024 u16 region
  const int tid  = threadIdx.x;
  const int lane = tid & 63, w = tid >> 6;
  const int l16  = lane & 15, quad = lane >> 4;
  const int lr8 = lane >> 3, lc8 = lane & 7;

  const int bx = blockIdx.x;
  const int qt = 15 - (bx >> 6);       // 128-row q-tiles, heavy first
  const int bh = bx & 63;
  const int h  = bh & 15, b = bh >> 4;

  const u16* qptr = qb + ((size_t)bh * TT + qt * 128) * DD;
  const u16* kptr = kb + (size_t)bh * TT * DD;
  const u16* vptr = vt + (size_t)bh * DD * TT;   // [D][T]

  // Q prologue: stage 128 rows x 64 d into Ks (scaled by 1/sqrt(D)*log2e),
  // then read both groups' frags. Ks is overwritten by K tiles in the loop.
  const float qscale = 0.125f * 1.44269504088896340736f;
  #pragma unroll
  for (int p = 0; p < 4; ++p) {
    const int r = w * 32 + p * 8 + lr8;
    u16x8 v = *reinterpret_cast<const u16x8*>(qptr + (size_t)r * DD + lc8 * 8);
    u16x8 o;
    #pragma unroll
    for (int e = 0; e < 8; ++e) o[e] = f2bf(bf2f(v[e]) * qscale);
    *reinterpret_cast<u16x8*>(&Ks[r * 64 + (lc8 ^ lr8) * 8]) = o;
  }
  __syncthreads();
  bf16x8 qf0[2], qf1[2];
  #pragma unroll
  for (int s = 0; s < 2; ++s) {
    qf0[s] = ld_bf16x8(&Ks[(w * 16 + l16) * 64 + ((s * 4 + quad) ^ (l16 & 7)) * 8]);
    qf1[s] = ld_bf16x8(&Ks[(64 + w * 16 + l16) * 64 + ((s * 4 + quad) ^ (l16 & 7)) * 8]);
  }

  float rsum0 = 0.f, rsum1 = 0.f;
  f32x4 O0[4], O1[4];
  #pragma unroll
  for (int j = 0; j < 4; ++j) { O0[j] = zero4(); O1[j] = zero4(); }

  const int nkt = qt + 1;              // 128-k tiles (exact causal coverage)
  for (int kt = 0; kt < nkt; ++kt) {
    __syncthreads();   // prior-tile frag reads (and Q-frag reads) complete
    {
      const u16* kt0 = kptr + (size_t)kt * 128 * DD;
      #pragma unroll
      for (int p = 0; p < 4; ++p) {      // K: 128 rows x 64 d (8 rows/inst)
        const int row = w * 32 + p * 8 + lr8;
        const int cs  = lc8 ^ lr8;       // row&7 == lr8
        gld_lds16(kt0 + (size_t)row * DD + cs * 8, &Ks[(w * 32 + p * 8) * 64]);
      }
      #pragma unroll
      for (int p = 0; p < 4; ++p) {      // V: 64 d-rows x 128 t (4 rows/inst)
        const int d  = w * 16 + p * 4 + (lane >> 4);
        const int cs = (lane & 15) ^ (d & 7);
        gld_lds16(vptr + (size_t)d * TT + kt * 128 + cs * 8,
                  &Vs[(w * 16 + p * 4) * 128]);
      }
    }
    wait_vm0();          // own DMA landed
    __syncthreads();     // everyone's DMA landed

    #pragma unroll
    for (int h2 = 0; h2 < 2; ++h2) {
      const int  last = (kt == qt);
      const bool g0on = !(last && h2 == 1);   // g0 done after its diagonal
      // S^T[k][q=l16] for both groups; kfr shared across groups.
      f32x4 St0[4], St1[4];
      #pragma unroll
      for (int j = 0; j < 4; ++j) { St0[j] = zero4(); St1[j] = zero4(); }
      #pragma unroll
      for (int s = 0; s < 2; ++s) {
        bf16x8 kfr[4];
        #pragma unroll
        for (int j = 0; j < 4; ++j)
          kfr[j] = ld_bf16x8(&Ks[(h2 * 64 + j * 16 + l16) * 64 +
                                 ((s * 4 + quad) ^ (l16 & 7)) * 8]);
        if (g0on) {
          #pragma unroll
          for (int j = 0; j < 4; ++j)
            St0[j] = __builtin_amdgcn_mfma_f32_16x16x32_bf16(kfr[j], qf0[s], St0[j], 0, 0, 0);
        }
        #pragma unroll
        for (int j = 0; j < 4; ++j)
          St1[j] = __builtin_amdgcn_mfma_f32_16x16x32_bf16(kfr[j], qf1[s], St1[j], 0, 0, 0);
      }
      if (last) {          // diagonal mask (k_local > q_local -> -inf)
        const int qg = w * 16 + l16;
        if (h2 == 0) {
          #pragma unroll
          for (int j = 0; j < 4; ++j)
            #pragma unroll
            for (int r = 0; r < 4; ++r)
              if (j * 16 + quad * 4 + r > qg) St0[j][r] = -__builtin_inff();
        } else {
          #pragma unroll
          for (int j = 0; j < 4; ++j)
            #pragma unroll
            for (int r = 0; r < 4; ++r)
              if (j * 16 + quad * 4 + r > qg) St1[j][r] = -__builtin_inff();
        }
      }

      // p = 2^S; accumulate l; repack into QP region (w*2+g)
      if (g0on) {
        #pragma unroll
        for (int j = 0; j < 4; ++j)
          #pragma unroll
          for (int r = 0; r < 4; ++r) {
            float p = __builtin_amdgcn_exp2f(St0[j][r]);
            St0[j][r] = p; rsum0 += p;
          }
        #pragma unroll
        for (int j = 0; j < 4; ++j) {
          union { bf16x4v bv; u16x4 u; } cv;
          cv.bv[0] = (__bf16)St0[j][0]; cv.bv[1] = (__bf16)St0[j][1];
          cv.bv[2] = (__bf16)St0[j][2]; cv.bv[3] = (__bf16)St0[j][3];
          const int c = j * 2 + (quad >> 1);
          const int off = (w * 2 + 0) * 1024 + l16 * 64 +
                          ((c ^ (l16 & 7)) << 3) + ((quad & 1) << 2);
          *reinterpret_cast<u16x4*>(&QP[off]) = cv.u;
        }
      }
      #pragma unroll
      for (int j = 0; j < 4; ++j)
        #pragma unroll
        for (int r = 0; r < 4; ++r) {
          float p = __builtin_amdgcn_exp2f(St1[j][r]);
          St1[j][r] = p; rsum1 += p;
        }
      #pragma unroll
      for (int j = 0; j < 4; ++j) {
        union { bf16x4v bv; u16x4 u; } cv;
        cv.bv[0] = (__bf16)St1[j][0]; cv.bv[1] = (__bf16)St1[j][1];
        cv.bv[2] = (__bf16)St1[j][2]; cv.bv[3] = (__bf16)St1[j][3];
        const int c = j * 2 + (quad >> 1);
        const int off = (w * 2 + 1) * 1024 + l16 * 64 +
                        ((c ^ (l16 & 7)) << 3) + ((quad & 1) << 2);
        *reinterpret_cast<u16x4*>(&QP[off]) = cv.u;
      }

      // PV: vf loaded once, feeds both groups
      #pragma unroll
      for (int s = 0; s < 2; ++s) {
        bf16x8 pf0, pf1;
        if (g0on)
          pf0 = ld_bf16x8(&QP[(w * 2 + 0) * 1024 + l16 * 64 +
                              ((s * 4 + quad) ^ (l16 & 7)) * 8]);
        pf1 = ld_bf16x8(&QP[(w * 2 + 1) * 1024 + l16 * 64 +
                            ((s * 4 + quad) ^ (l16 & 7)) * 8]);
        #pragma unroll
        for (int j = 0; j < 4; ++j) {
          bf16x8 vf = ld_bf16x8(&Vs[(j * 16 + l16) * 128 +
                                    ((h2 * 8 + s * 4 + quad) ^ (l16 & 7)) * 8]);
          if (g0on)
            O0[j] = __builtin_amdgcn_mfma_f32_16x16x32_bf16(pf0, vf, O0[j], 0, 0, 0);
          O1[j] = __builtin_amdgcn_mfma_f32_16x16x32_bf16(pf1, vf, O1[j], 0, 0, 0);
        }
      }
    }
  }

  // epilogue per group: reduce l across quads, O /= l, write y
  #pragma unroll
  for (int g = 0; g < 2; ++g) {
    float rs = (g == 0) ? rsum0 : rsum1;
    rs += __shfl_xor(rs, 16);
    rs += __shfl_xor(rs, 32);
    const float linv = 1.0f / rs;
    f32x4 lv;
    #pragma unroll
    for (int r = 0; r < 4; ++r) lv[r] = lane_pull(linv, quad * 4 + r);
    #pragma unroll
    for (int j = 0; j < 4; ++j) {
      f32x4 o = (g == 0) ? O0[j] : O1[j];
      o *= lv;
      #pragma unroll
      for (int r = 0; r < 4; ++r) {
        int t  = qt * 128 + g * 64 + w * 16 + quad * 4 + r;
        int ch = h * 64 + j * 16 + l16;
        y[(size_t)(b * TT + t) * CC + ch] = f2bf(o[r]);
      }
    }
  }
}

extern "C" void kernel_launch(void* const* d_in, const int* in_sizes, int n_in,
                              void* d_out, int out_size, void* d_ws, size_t ws_size,
                              hipStream_t stream) {
  const float* x  = (const float*)d_in[0];   // [B,T,C]
  const float* Wa = (const float*)d_in[1];   // [C,3C]
  const float* Wp = (const float*)d_in[2];   // [C,C]
  float* out = (float*)d_out;                // [B,T,C] fp32

  u16* ws   = (u16*)d_ws;
  u16* xb   = ws;                             // M*C
  u16* Wab  = xb   + (size_t)MM * CC;         // 3C*C (W_attn^T)
  u16* Wpb  = Wab  + (size_t)3 * CC * CC;     // C*C  (W_proj^T)
  u16* qbuf = Wpb  + (size_t)CC * CC;         // [B,H,T,D]
  u16* kbuf = qbuf + (size_t)MM * CC;         // [B,H,T,D]
  u16* vtb  = kbuf + (size_t)MM * CC;         // [B,H,D,T]
  u16* yb   = vtb  + (size_t)MM * CC;         // [B,T,C]

  k_prep<<<NC4B + 3072 + 1024, 256, 0, stream>>>(x, xb, Wa, Wab, Wp, Wpb);
  k_gemm_bt<1><<<dim3(3 * CC / 128, MM / 128), 256, 0, stream>>>(
      xb, Wab, nullptr, qbuf, kbuf, vtb, 3 * CC, CC);
  k_attn<<<64 * 16, 256, 0, stream>>>(qbuf, kbuf, vtb, yb);
  k_gemm_bt<0><<<dim3(CC / 128, MM / 128), 256, 0, stream>>>(
      yb, Wpb, out, nullptr, nullptr, nullptr, CC, CC);
}